// Round 2
// 292.077 us; speedup vs baseline: 1.0462x; 1.0462x over previous
//
#include <hip/hip_runtime.h>

// QRNN3D fused: conv3d(16->48,3x3x3,SAME) + gates + fo-pool via bf16 MFMA.
// Round 4 (from 155us/dispatch, VALU 46% / Mfma 24% / ~30% stall):
//  - rcp fast path: replace 24 IEEE f32 div sequences/thread/t with v_rcp_f32
//  - hoist t-invariant addressing: ring tap offsets roff[s] precomputed; kd is
//    compile-time for all s except s=4 (taps 8/9); slot bases are 3 rotating
//    scalars -> ~1 v_add per s instead of /9 and /3 magic-mul chains
//  - staging loads: t-invariant 32-bit element offsets + uniform base
//    (xin + tc*HW) -> saddr-form global_load, 0 addr VALU per load
//  - raw barriers (s_waitcnt lgkmcnt(0); s_barrier) without the vmcnt(0)
//    drain, plus rv double-buffer: the batch consumed by write_lds was issued
//    one full iteration earlier, so loads stay in flight across barriers.
//    t-loop 2x-unrolled so rvA/rvB roles are compile-time (no scratch).
// (Round 5: resubmit of round 4 — bench infra failed before any measurement.)
//
// GEMM: gates[48][px] = W[48][K=448] * im2col[K][px]; K = tap*16+ic,
// tap = kd*9+kh*3+kw (27 real, pad tap 27 has W==0).
// mfma_f32_16x16x32_bf16: A[m][k=q*8+j] = W, B[k][n=px], C/D col=lane&15,
// row=q*4+reg. Wave owns 32 px x 16 hidden ch; z/f/o accs lane-aligned so
// the t-recurrence is per-lane register math.

typedef __attribute__((ext_vector_type(8))) short short8;
typedef __attribute__((ext_vector_type(4))) float float4v;

#define TD 31
#define HW (128 * 128)
#define LH 6                         // 4 tile rows + 2 halo
#define LW 34                        // 32 tile cols + 2 halo
#define UNITS (LH * 2 * LW)          // 408 short8 units per plane
#define NSLOT 3
#define SLOTB (UNITS * 16)           // 6528 B per ring slot
#define WUNITS (14 * 3 * 64)         // weight LDS: [s][g][lane] -> short8

__device__ __forceinline__ short f2bf(float f) {
    unsigned u = __float_as_uint(f);
    u = (u + 0x7FFFu + ((u >> 16) & 1u)) >> 16;   // RNE
    return (short)u;
}

__device__ __forceinline__ float frcp(float x) { return __builtin_amdgcn_rcpf(x); }

// Barrier WITHOUT the compiler's vmcnt(0) drain. lgkmcnt(0) orders LDS
// (reads of the slot being overwritten / writes being published); global
// loads target private registers, so their completion is handled by the
// compiler's per-register vmcnt tracking at the point of use.
#define BARRIER() asm volatile("s_waitcnt lgkmcnt(0)\n\ts_barrier" ::: "memory")

__global__ __launch_bounds__(256, 2) void qrnn_mfma3(
    const float* __restrict__ x,     // (4,16,31,128,128)
    const float* __restrict__ wt,    // (48,16,27)
    const float* __restrict__ bias,  // (48)
    float* __restrict__ out)         // (4,16,31,128,128)
{
    __shared__ short8 wlds[WUNITS];          // 43008 B
    __shared__ short8 ring[NSLOT * UNITS];   // 19584 B

    const int tid  = threadIdx.x;
    const int lane = tid & 63;
    const int wv   = tid >> 6;       // wave id = h row in tile
    const int q    = lane >> 4;
    const int px   = lane & 15;
    const int b    = blockIdx.x;     // 512 blocks
    const int n    = b >> 7;
    const int h0   = ((b >> 2) & 31) * 4;
    const int w0   = (b & 3) * 32;

    const float* xin = x + (size_t)n * (16 * TD * HW);

    // ---- fill weight LDS once: wlds[(s*3+g)*64 + lane] = A-frag ----
    for (int k = 0; k < 11; ++k) {
        int u = tid + k * 256;
        if (u < WUNITS) {
            int l = u & 63, rest = u >> 6;
            int g = rest % 3, s = rest / 3;
            int qq = l >> 4, m = l & 15;
            short8 a;
#pragma unroll
            for (int j = 0; j < 8; ++j) {
                int kk = s * 32 + qq * 8 + j;
                int tap = kk >> 4, ic = kk & 15;
                float v = (tap < 27) ? wt[((size_t)((g * 16 + m) * 16 + ic)) * 27 + tap] : 0.f;
                a[j] = f2bf(v);
            }
            wlds[u] = a;
        }
    }

    // ---- staging: t-invariant 32-bit element offsets + validity ----
    int  s_off[2][8];
    bool s_in[2], s_ok[2];
#pragma unroll
    for (int i = 0; i < 2; ++i) {
        int u    = tid + i * 256;
        int uu   = (u < UNITS) ? u : 0;
        int wp   = uu % LW;
        int rest = uu / LW;
        int ck   = rest & 1;
        int hp   = rest >> 1;
        int hh   = h0 + hp - 1;
        int ww   = w0 + wp - 1;
        s_in[i] = (u < UNITS);
        s_ok[i] = s_in[i] && ((unsigned)hh < 128u) && ((unsigned)ww < 128u);
        int hc = hh < 0 ? 0 : (hh > 127 ? 127 : hh);   // clamped safe coords
        int wc = ww < 0 ? 0 : (ww > 127 ? 127 : ww);
#pragma unroll
        for (int j = 0; j < 8; ++j)
            s_off[i][j] = ((ck * 8 + j) * TD) * HW + hc * 128 + wc;
    }

    float rvA[2][8], rvB[2][8];

    // loads are ALWAYS issued (safe clamped address) so the in-flight VMEM
    // count is deterministic; zero-fill via select, never via branch.
    auto issue = [&](int tt, float (&rv)[2][8]) {
        const bool tz = ((unsigned)tt >= 31u);
        const int  tc = tz ? 0 : tt;
        const float* basep = xin + (size_t)tc * HW;   // uniform -> SGPR base
#pragma unroll
        for (int i = 0; i < 2; ++i) {
            bool ok = s_ok[i] && !tz;
#pragma unroll
            for (int j = 0; j < 8; ++j) {
                float v = basep[s_off[i][j]];
                rv[i][j] = ok ? v : 0.f;
            }
        }
    };

    auto lds_write = [&](int wu, float (&rv)[2][8]) {
#pragma unroll
        for (int i = 0; i < 2; ++i) {
            if (s_in[i]) {
                short8 v;
#pragma unroll
                for (int j = 0; j < 8; ++j) v[j] = f2bf(rv[i][j]);
                ring[wu + tid + i * 256] = v;
            }
        }
    };

    // ---- ring tap offsets (t-invariant). kd compile-time except s=4. ----
    int roff[14];
#pragma unroll
    for (int s = 0; s < 14; ++s) {
        int T = 2 * s + (q >> 1); if (T > 26) T = 26;
        int kd = T / 9, rr = T - kd * 9, kh = rr / 3, kw = rr - kh * 3;
        roff[s] = (((wv + kh) * 2 + (q & 1)) * LW + px + kw) * 16;  // bytes
    }
    const int kd4 = q >> 1;          // kd for s==4: taps 8 (kd=0) / 9 (kd=1)

    // bias per lane: channel = g*16 + q*4 + r
    float4v bv[3];
#pragma unroll
    for (int g = 0; g < 3; ++g)
        bv[g] = (float4v){bias[g * 16 + q * 4 + 0], bias[g * 16 + q * 4 + 1],
                          bias[g * 16 + q * 4 + 2], bias[g * 16 + q * 4 + 3]};

    float* po = out + ((size_t)(n * 16 + q * 4) * TD) * HW
                    + (size_t)(h0 + wv) * 128 + w0 + px;
    float cst[2][4] = {{0.f,0.f,0.f,0.f},{0.f,0.f,0.f,0.f}};

    // ---- prologue: planes -1,0,1 into slots 0,1,2; plane 2 in flight ----
    issue(-1, rvA); lds_write(0,         rvA);
    issue(0,  rvA); lds_write(UNITS,     rvA);
    issue(1,  rvA); lds_write(2 * UNITS, rvA);
    issue(2,  rvA);
    BARRIER();

    // body(t): rvW holds plane t+2 (issued one iter ago); issues plane t+3
    // into rvI. pk[j] = ((t+j)%3)*SLOTB scalar slot bases; wu = (t%3)*UNITS.
    auto body = [&](int t, int pk0, int pk1, int pk2, int wu,
                    float (&rvW)[2][8], float (&rvI)[2][8]) {
        issue(t + 3, rvI);           // in flight across this whole iteration

        float4v acc[2][3];
#pragma unroll
        for (int g = 0; g < 3; ++g) { acc[0][g] = bv[g]; acc[1][g] = bv[g]; }

        const int pk[3] = {pk0, pk1, pk2};
        constexpr int kdt[14] = {0,0,0,0, 0 /*s=4 special*/, 1,1,1,1, 2,2,2,2,2};
        const char* ringb = (const char*)ring;
#pragma unroll
        for (int s = 0; s < 14; ++s) {
            int sb = (s == 4) ? (kd4 ? pk1 : pk0) : pk[kdt[s]];
            const short8* bp = (const short8*)(ringb + sb + roff[s]);
            short8 b0 = bp[0];           // ds_read_b128, conflict-free
            short8 b1 = bp[16];          // +16 w cols, offset:256 immediate
#pragma unroll
            for (int g = 0; g < 3; ++g) {
                short8 wf = wlds[(s * 3 + g) * 64 + lane];
                acc[0][g] = __builtin_amdgcn_mfma_f32_16x16x32_bf16(wf, b0, acc[0][g], 0, 0, 0);
                acc[1][g] = __builtin_amdgcn_mfma_f32_16x16x32_bf16(wf, b1, acc[1][g], 0, 0, 0);
            }
        }
        BARRIER();                   // all waves done reading slot t%3
        lds_write(wu, rvW);          // plane t+2 -> slot t%3

        // activations + fo-pool + store (rcp fast path)
#pragma unroll
        for (int tile = 0; tile < 2; ++tile) {
#pragma unroll
            for (int r = 0; r < 4; ++r) {
                float az = acc[tile][0][r];
                float af = acc[tile][1][r];
                float ao = acc[tile][2][r];
                float z = 1.f - 2.f * frcp(__expf(2.f * az) + 1.f);
                float f = frcp(1.f + __expf(-af));
                float o = frcp(1.f + __expf(-ao));
                float c = f * cst[tile][r] + (1.f - f) * z;
                cst[tile][r] = c;
                po[(size_t)r * (TD * HW) + tile * 16] = o * c;
            }
        }
        po += HW;
        BARRIER();                   // ds_writes visible before next iter
    };

    int pk0 = 0, pk1 = SLOTB, pk2 = 2 * SLOTB;
    int wu = 0;
    for (int t = 0; t < 30; t += 2) {
        body(t,     pk0, pk1, pk2, wu,  rvA, rvB);
        int wu1 = (wu == 2 * UNITS) ? 0 : wu + UNITS;
        body(t + 1, pk1, pk2, pk0, wu1, rvB, rvA);
        int t0 = pk0; pk0 = pk2; pk2 = pk1; pk1 = t0;   // rotate by 2
        wu = (wu1 == 2 * UNITS) ? 0 : wu1 + UNITS;
    }
    body(30, pk0, pk1, pk2, wu, rvA, rvB);   // tail (issues dead plane 33)
}

extern "C" void kernel_launch(void* const* d_in, const int* in_sizes, int n_in,
                              void* d_out, int out_size, void* d_ws, size_t ws_size,
                              hipStream_t stream) {
    const float* x    = (const float*)d_in[0];
    const float* wt   = (const float*)d_in[1];
    const float* bias = (const float*)d_in[2];
    float* out = (float*)d_out;

    // grid: n(4) x hblk(32) x wblk(4) = 512 blocks of 256 threads (4 waves)
    qrnn_mfma3<<<dim3(512), dim3(256), 0, stream>>>(x, wt, bias, out);
}

// Round 3
// 290.109 us; speedup vs baseline: 1.0533x; 1.0068x over previous
//
#include <hip/hip_runtime.h>

// QRNN3D fused: conv3d(16->48,3x3x3,SAME) + gates + fo-pool via bf16 MFMA.
// Round 6 (from 141us/dispatch, VALU 30% / Mfma 26.5% / ~40% no-issue):
//  - NSLOT=4 ring: plane t+2 overwrites plane t-2 (last read at t-1) ->
//    write-after-read barrier DELETED; ONE barrier per t instead of two.
//    Ring 26112B + weights 43008B = 69120B -> dynamic LDS (>64K static cap),
//    2 blocks/CU = 138KB < 160KB preserved.
//  - v_cvt_pk_bf16_f32 (inline asm, RNE) packs 2 f32->bf16x2: replaces the
//    4-op manual-RNE f2bf x16/t in the staging path.
//  - zero-select removal: ring slots pre-zeroed once; loads unconditional
//    (clamped addrs always valid); stores guarded by s_ok; tz planes
//    zero-written via uniform branch (t>=29 only).
//
// GEMM: gates[48][px] = W[48][K=448] * im2col[K][px]; K = tap*16+ic,
// tap = kd*9+kh*3+kw (27 real, pad tap 27 has W==0).
// mfma_f32_16x16x32_bf16: A[m][k=q*8+j] = W, B[k][n=px], C/D col=lane&15,
// row=q*4+reg. Wave owns 32 px x 16 hidden ch; z/f/o accs lane-aligned so
// the t-recurrence is per-lane register math.

typedef __attribute__((ext_vector_type(8))) short short8;
typedef __attribute__((ext_vector_type(4))) float float4v;

#define TD 31
#define HW (128 * 128)
#define LH 6                         // 4 tile rows + 2 halo
#define LW 34                        // 32 tile cols + 2 halo
#define UNITS (LH * 2 * LW)          // 408 short8 units per plane
#define NSLOT 4
#define SLOTB (UNITS * 16)           // 6528 B per ring slot
#define WUNITS (14 * 3 * 64)         // 2688 weight units
#define SMEM_BYTES ((WUNITS + NSLOT * UNITS) * 16)   // 69120

__device__ __forceinline__ short f2bf(float f) {
    unsigned u = __float_as_uint(f);
    u = (u + 0x7FFFu + ((u >> 16) & 1u)) >> 16;   // RNE
    return (short)u;
}

__device__ __forceinline__ float frcp(float x) { return __builtin_amdgcn_rcpf(x); }

__device__ __forceinline__ unsigned cvtpk(float lo, float hi) {
    unsigned r;
    asm("v_cvt_pk_bf16_f32 %0, %1, %2" : "=v"(r) : "v"(lo), "v"(hi));
    return r;
}

// Barrier WITHOUT the compiler's vmcnt(0) drain. lgkmcnt(0) orders LDS;
// global loads target private registers (compiler-tracked vmcnt at use).
#define BARRIER() asm volatile("s_waitcnt lgkmcnt(0)\n\ts_barrier" ::: "memory")

__global__ __launch_bounds__(256, 2) void qrnn_mfma4(
    const float* __restrict__ x,     // (4,16,31,128,128)
    const float* __restrict__ wt,    // (48,16,27)
    const float* __restrict__ bias,  // (48)
    float* __restrict__ out)         // (4,16,31,128,128)
{
    extern __shared__ short8 smem[];
    short8* wlds = smem;             // [WUNITS]
    short8* ring = smem + WUNITS;    // [NSLOT*UNITS]

    const int tid  = threadIdx.x;
    const int lane = tid & 63;
    const int wv   = tid >> 6;       // wave id = h row in tile
    const int q    = lane >> 4;
    const int px   = lane & 15;
    const int b    = blockIdx.x;     // 512 blocks
    const int n    = b >> 7;
    const int h0   = ((b >> 2) & 31) * 4;
    const int w0   = (b & 3) * 32;

    const float* xin = x + (size_t)n * (16 * TD * HW);

    // ---- fill weight LDS once: wlds[(s*3+g)*64 + lane] = A-frag ----
    for (int k = 0; k < 11; ++k) {
        int u = tid + k * 256;
        if (u < WUNITS) {
            int l = u & 63, rest = u >> 6;
            int g = rest % 3, s = rest / 3;
            int qq = l >> 4, m = l & 15;
            short8 a;
#pragma unroll
            for (int j = 0; j < 8; ++j) {
                int kk = s * 32 + qq * 8 + j;
                int tap = kk >> 4, ic = kk & 15;
                float v = (tap < 27) ? wt[((size_t)((g * 16 + m) * 16 + ic)) * 27 + tap] : 0.f;
                a[j] = f2bf(v);
            }
            wlds[u] = a;
        }
    }
    // ---- zero all ring slots once (halo-invalid units stay 0 forever;
    //      plane -1 = slot 3 stays 0) ----
    {
        short8 z = (short8)0;
        for (int k = 0; k < 7; ++k) {
            int u = tid + k * 256;
            if (u < NSLOT * UNITS) ring[u] = z;
        }
    }

    // ---- staging: t-invariant 32-bit element offsets + validity ----
    int  s_off[2][8];
    bool s_ok[2];
#pragma unroll
    for (int i = 0; i < 2; ++i) {
        int u    = tid + i * 256;
        int uu   = (u < UNITS) ? u : 0;
        int wp   = uu % LW;
        int rest = uu / LW;
        int ck   = rest & 1;
        int hp   = rest >> 1;
        int hh   = h0 + hp - 1;
        int ww   = w0 + wp - 1;
        s_ok[i] = (u < UNITS) && ((unsigned)hh < 128u) && ((unsigned)ww < 128u);
        int hc = hh < 0 ? 0 : (hh > 127 ? 127 : hh);   // clamped safe coords
        int wc = ww < 0 ? 0 : (ww > 127 ? 127 : ww);
#pragma unroll
        for (int j = 0; j < 8; ++j)
            s_off[i][j] = ((ck * 8 + j) * TD) * HW + hc * 128 + wc;
    }

    float rvA[2][8], rvB[2][8];

    // loads ALWAYS issued at safe clamped addresses; no per-lane select.
    auto issue = [&](int tt, float (&rv)[2][8]) {
        const int tc = ((unsigned)tt >= 31u) ? 0 : tt;
        const float* basep = xin + (size_t)tc * HW;   // uniform -> SGPR base
#pragma unroll
        for (int i = 0; i < 2; ++i)
#pragma unroll
            for (int j = 0; j < 8; ++j)
                rv[i][j] = basep[s_off[i][j]];
    };

    // tz is wave-uniform: zero-write path is a uniform branch (t>=29 only).
    auto lds_write = [&](int wu, float (&rv)[2][8], bool tz) {
        if (!tz) {
#pragma unroll
            for (int i = 0; i < 2; ++i) {
                if (s_ok[i]) {
                    union { short8 s; unsigned u[4]; } v;
#pragma unroll
                    for (int k = 0; k < 4; ++k)
                        v.u[k] = cvtpk(rv[i][2 * k], rv[i][2 * k + 1]);
                    ring[wu + tid + i * 256] = v.s;
                }
            }
        } else {
            short8 z = (short8)0;
#pragma unroll
            for (int i = 0; i < 2; ++i)
                if (s_ok[i]) ring[wu + tid + i * 256] = z;
        }
    };

    // ---- ring tap offsets (t-invariant). kd compile-time except s=4. ----
    int roff[14];
#pragma unroll
    for (int s = 0; s < 14; ++s) {
        int T = 2 * s + (q >> 1); if (T > 26) T = 26;
        int kd = T / 9, rr = T - kd * 9, kh = rr / 3, kw = rr - kh * 3;
        roff[s] = (((wv + kh) * 2 + (q & 1)) * LW + px + kw) * 16;  // bytes
    }
    const int kd4 = q >> 1;          // kd for s==4: taps 8 (kd=0) / 9 (kd=1)

    // bias per lane: channel = g*16 + q*4 + r
    float4v bv[3];
#pragma unroll
    for (int g = 0; g < 3; ++g)
        bv[g] = (float4v){bias[g * 16 + q * 4 + 0], bias[g * 16 + q * 4 + 1],
                          bias[g * 16 + q * 4 + 2], bias[g * 16 + q * 4 + 3]};

    float* po = out + ((size_t)(n * 16 + q * 4) * TD) * HW
                    + (size_t)(h0 + wv) * 128 + w0 + px;
    float cst[2][4] = {{0.f,0.f,0.f,0.f},{0.f,0.f,0.f,0.f}};

    // ---- prologue. slot(p) = p&3; plane -1 -> slot 3 (zeros, pre-filled).
    // Barrier first: plane writes touch units zero-filled by OTHER threads.
    BARRIER();
    issue(0, rvA); lds_write(0 * UNITS, rvA, false);
    issue(1, rvA); lds_write(1 * UNITS, rvA, false);
    issue(2, rvA);                   // consumed by body(0)
    BARRIER();

    // body(t): r0..r3 = byte bases of slots holding planes t-1..t+2.
    // Reads r0..r2; writes plane t+2 into r3 (held plane t-2, last read at
    // t-1 -> NO pre-write barrier needed). Single barrier at end of t.
    auto body = [&](int t, int r0, int r1, int r2, int r3,
                    float (&rvW)[2][8], float (&rvI)[2][8]) {
        issue(t + 3, rvI);           // in flight across this whole iteration

        float4v acc[2][3];
#pragma unroll
        for (int g = 0; g < 3; ++g) { acc[0][g] = bv[g]; acc[1][g] = bv[g]; }

        const int pk[3] = {r0, r1, r2};
        constexpr int kdt[14] = {0,0,0,0, 0 /*s=4 special*/, 1,1,1,1, 2,2,2,2,2};
        const char* ringb = (const char*)ring;
#pragma unroll
        for (int s = 0; s < 14; ++s) {
            int sb = (s == 4) ? (kd4 ? r1 : r0) : pk[kdt[s]];
            const short8* bp = (const short8*)(ringb + sb + roff[s]);
            short8 b0 = bp[0];           // ds_read_b128, conflict-free
            short8 b1 = bp[16];          // +16 w cols, offset:256 immediate
#pragma unroll
            for (int g = 0; g < 3; ++g) {
                short8 wf = wlds[(s * 3 + g) * 64 + lane];
                acc[0][g] = __builtin_amdgcn_mfma_f32_16x16x32_bf16(wf, b0, acc[0][g], 0, 0, 0);
                acc[1][g] = __builtin_amdgcn_mfma_f32_16x16x32_bf16(wf, b1, acc[1][g], 0, 0, 0);
            }
        }
        lds_write(r3 >> 4, rvW, t >= 29);   // plane t+2 (zeros for t>=29)

        // activations + fo-pool + store (rcp fast path)
#pragma unroll
        for (int tile = 0; tile < 2; ++tile) {
#pragma unroll
            for (int r = 0; r < 4; ++r) {
                float az = acc[tile][0][r];
                float af = acc[tile][1][r];
                float ao = acc[tile][2][r];
                float z = 1.f - 2.f * frcp(__expf(2.f * az) + 1.f);
                float f = frcp(1.f + __expf(-af));
                float o = frcp(1.f + __expf(-ao));
                float c = f * cst[tile][r] + (1.f - f) * z;
                cst[tile][r] = c;
                po[(size_t)r * (TD * HW) + tile * 16] = o * c;
            }
        }
        po += HW;
        BARRIER();   // my reads of r0..r2 done (lgkmcnt 0) + my write of r3
                     // visible -> next iter may read r3's plane & reuse r0's slot
    };

    // rotating slot bases: start = slots of planes (-1,0,1,2) = (3,0,1,2)
    int r0 = 3 * SLOTB, r1 = 0, r2 = SLOTB, r3 = 2 * SLOTB;
    for (int t = 0; t < 30; t += 2) {
        body(t,     r0, r1, r2, r3, rvA, rvB);
        body(t + 1, r1, r2, r3, r0, rvB, rvA);
        int a = r0, c = r1;          // advance by 2 (mod 4)
        r0 = r2; r1 = r3; r2 = a; r3 = c;
    }
    body(30, r0, r1, r2, r3, rvA, rvB);   // tail (issues dead plane 33)
}

extern "C" void kernel_launch(void* const* d_in, const int* in_sizes, int n_in,
                              void* d_out, int out_size, void* d_ws, size_t ws_size,
                              hipStream_t stream) {
    const float* x    = (const float*)d_in[0];
    const float* wt   = (const float*)d_in[1];
    const float* bias = (const float*)d_in[2];
    float* out = (float*)d_out;

    static bool configured = false;
    if (!configured) {
        hipFuncSetAttribute((const void*)qrnn_mfma4,
                            hipFuncAttributeMaxDynamicSharedMemorySize,
                            SMEM_BYTES);
        configured = true;
    }

    // grid: n(4) x hblk(32) x wblk(4) = 512 blocks of 256 threads (4 waves)
    qrnn_mfma4<<<dim3(512), dim3(256), SMEM_BYTES, stream>>>(x, wt, bias, out);
}